// Round 12
// baseline (37.539 us; speedup 1.0000x reference)
//
#include <hip/hip_runtime.h>
#include <hip/hip_bf16.h>
#include <float.h>

#define N_LOC 101
#define TAUC 0.5f
#define RAC  0.5f
#define EPSV 1e-4f

__device__ __forceinline__ float wsum64(float v) {
    #pragma unroll
    for (int off = 32; off; off >>= 1) v += __shfl_xor(v, off);
    return v;
}

__device__ __forceinline__ void fma4(float* acc, float s, float4 v) {
    acc[0] += s * v.x; acc[1] += s * v.y;
    acc[2] += s * v.z; acc[3] += s * v.w;
}

// ---------------------------------------------------------------------------
// fused4_kernel: identical to round-11 (best: 21.36 us timed).
// THIS ROUND IS AN A/B PROBE: kernel_launch launches it TWICE (idempotent —
// reads only inputs, rewrites identical outputs). dur_us(2x) - dur_us(1x)
// isolates the true per-launch kernel cost vs the harness replay floor.
// ---------------------------------------------------------------------------
__global__ __launch_bounds__(256, 4) void fused4_kernel(
    const float* __restrict__ x,
    const float* __restrict__ p0, const float* __restrict__ p1,
    const float* __restrict__ p2, const float* __restrict__ p3,
    const float* __restrict__ p4, const float* __restrict__ p5,
    const float* __restrict__ p6, const float* __restrict__ p7,
    const float* __restrict__ W1, const float* __restrict__ b1,
    const float* __restrict__ W2, const float* __restrict__ b2,
    const float* __restrict__ W3, const float* __restrict__ b3,
    float* __restrict__ out_pdf, float* __restrict__ out_z,
    float* __restrict__ out_err, int B)
{
    __shared__ float xs [4 * 64];        // 1 KB
    __shared__ float hp [2][4 * 132];    // K-split partials, 4.2 KB
    __shared__ float hs1[4 * 132];       // h1, 2.1 KB
    __shared__ float hs2[4 * 132];       // h2, 2.1 KB

    const int t   = threadIdx.x;
    const int r0b = blockIdx.x * 4;

    // ---- stage x tile (4 x 64 = 256 floats)
    if (t < 64)
        *reinterpret_cast<float4*>(&xs[t * 4]) =
            *reinterpret_cast<const float4*>(&x[r0b * 64 + t * 4]);
    __syncthreads();

    const int rowg = (t >> 5) & 3;      // 0..3
    const int j0   = (t & 31) * 4;      // 0..124
    const int kh   = t >> 7;            // 0,1 : K-split half

    // ---- phase 1: h1 = relu(x @ W1 + b1), K=64 split 32+32
    {
        float acc[4] = {0.f, 0.f, 0.f, 0.f};
        const int kb = kh * 32;
        #pragma unroll
        for (int kk = 0; kk < 32; ++kk) {
            const float xv = xs[rowg * 64 + kb + kk];
            const float4 w = *reinterpret_cast<const float4*>(&W1[(kb + kk) * 128 + j0]);
            fma4(acc, xv, w);
        }
        float4 o; o.x = acc[0]; o.y = acc[1]; o.z = acc[2]; o.w = acc[3];
        *reinterpret_cast<float4*>(&hp[kh][rowg * 132 + j0]) = o;
    }
    __syncthreads();
    if (t < 128) {
        const int rr = t >> 5, jj = (t & 31) * 4;
        const float4 bv = *reinterpret_cast<const float4*>(&b1[jj]);
        const float4 q0 = *reinterpret_cast<const float4*>(&hp[0][rr * 132 + jj]);
        const float4 q1 = *reinterpret_cast<const float4*>(&hp[1][rr * 132 + jj]);
        float4 o;
        o.x = fmaxf(q0.x + q1.x + bv.x, 0.f);
        o.y = fmaxf(q0.y + q1.y + bv.y, 0.f);
        o.z = fmaxf(q0.z + q1.z + bv.z, 0.f);
        o.w = fmaxf(q0.w + q1.w + bv.w, 0.f);
        *reinterpret_cast<float4*>(&hs1[rr * 132 + jj]) = o;
    }
    __syncthreads();

    // ---- phase 2: h2 = relu(h1 @ W2 + b2), K=128 split 64+64
    {
        float acc[4] = {0.f, 0.f, 0.f, 0.f};
        const int kb = kh * 64;
        #pragma unroll
        for (int kk = 0; kk < 64; ++kk) {
            const float hv = hs1[rowg * 132 + kb + kk];
            const float4 w = *reinterpret_cast<const float4*>(&W2[(kb + kk) * 128 + j0]);
            fma4(acc, hv, w);
        }
        float4 o; o.x = acc[0]; o.y = acc[1]; o.z = acc[2]; o.w = acc[3];
        *reinterpret_cast<float4*>(&hp[kh][rowg * 132 + j0]) = o;
    }
    __syncthreads();
    if (t < 128) {
        const int rr = t >> 5, jj = (t & 31) * 4;
        const float4 bv = *reinterpret_cast<const float4*>(&b2[jj]);
        const float4 q0 = *reinterpret_cast<const float4*>(&hp[0][rr * 132 + jj]);
        const float4 q1 = *reinterpret_cast<const float4*>(&hp[1][rr * 132 + jj]);
        float4 o;
        o.x = fmaxf(q0.x + q1.x + bv.x, 0.f);
        o.y = fmaxf(q0.y + q1.y + bv.y, 0.f);
        o.z = fmaxf(q0.z + q1.z + bv.z, 0.f);
        o.w = fmaxf(q0.w + q1.w + bv.w, 0.f);
        *reinterpret_cast<float4*>(&hs2[rr * 132 + jj]) = o;
    }
    __syncthreads();

    // ---- phase 3 + softmax: wave wid <-> row wid; lane: e = lane&7, kc = lane>>3
    const int wid  = t >> 6;            // 0..3
    const int lane = t & 63;
    const int e    = lane & 7;
    const int kc   = lane >> 3;
    float acc3 = 0.f;
    #pragma unroll
    for (int i = 0; i < 16; ++i)
        acc3 += hs2[wid * 132 + kc * 16 + i] * W3[(kc * 16 + i) * 8 + e];
    acc3 += __shfl_xor(acc3, 8);
    acc3 += __shfl_xor(acc3, 16);
    acc3 += __shfl_xor(acc3, 32);
    const float logit = acc3 + b3[e];
    float m = logit;
    m = fmaxf(m, __shfl_xor(m, 1));
    m = fmaxf(m, __shfl_xor(m, 2));
    m = fmaxf(m, __shfl_xor(m, 4));
    const float ex = expf(logit - m);
    float s = ex;
    s += __shfl_xor(s, 1);
    s += __shfl_xor(s, 2);
    s += __shfl_xor(s, 4);
    const float wgt = ex / s;          // softmax weight for expert e (this row)

    float wv8[8];
    #pragma unroll
    for (int e2 = 0; e2 < 8; ++e2) wv8[e2] = __shfl(wgt, e2);  // lane e2: e==e2, kc==0

    // ---- solve: wave wid solves row r0b + wid (verified closed-form)
    const int row = r0b + wid;
    const long base = (long)row * N_LOC;
    const int n1 = lane, n2 = lane + 64;
    const bool v2 = (n2 < N_LOC);
    const float s1 = n1 * 0.01f, s2 = n2 * 0.01f;

    float pdf1, pdf2;
    {
        const float* pp[8] = { p0+base, p1+base, p2+base, p3+base,
                               p4+base, p5+base, p6+base, p7+base };
        pdf1 = 0.f; pdf2 = 0.f;
        #pragma unroll
        for (int ee = 0; ee < 8; ++ee) {
            pdf1 += wv8[ee] * pp[ee][n1];
            pdf2 += wv8[ee] * (v2 ? pp[ee][n2] : 0.f);
        }
    }
    out_pdf[base + n1] = pdf1;
    if (v2) out_pdf[base + n2] = pdf2;

    // row scalars
    const float P   = wsum64(pdf1 + pdf2);
    const float Sp  = wsum64(pdf1*s1  + pdf2*s2);
    const float Sp2 = wsum64(pdf1*s1*s1 + pdf2*s2*s2);
    const float Q   = P   + (float)N_LOC * EPSV;
    const float Sq  = Sp  + 50.5f  * EPSV;
    const float Sq2 = Sp2 + 33.835f * EPSV;

    // inclusive scans of p and p*s over both halves
    float ap = pdf1, bp = pdf2, aps = pdf1*s1, bps = pdf2*s2;
    #pragma unroll
    for (int off = 1; off < 64; off <<= 1) {
        float t0 = __shfl_up(ap,  off);
        float t1 = __shfl_up(bp,  off);
        float t2 = __shfl_up(aps, off);
        float t3 = __shfl_up(bps, off);
        if (lane >= off) { ap += t0; bp += t1; aps += t2; bps += t3; }
    }
    const float TaP  = __shfl(ap,  63);
    const float TaPs = __shfl(aps, 63);
    float eC1 = __shfl_up(ap,  1); if (lane == 0) eC1 = 0.f;
    float eB1 = __shfl_up(aps, 1); if (lane == 0) eB1 = 0.f;
    float eC2 = __shfl_up(bp,  1); if (lane == 0) eC2 = 0.f;
    float eB2 = __shfl_up(bps, 1); if (lane == 0) eB2 = 0.f;
    eC2 += TaP; eB2 += TaPs;

    auto evalc = [&](int k, float C, float Bv, float& zout) -> float {
        const float lo = (k == 0)   ? 0.f : (k - 1) * 0.01f;
        const float hi = (k <= 100) ? k * 0.01f : 1.f;
        float zu = (Sq + (1.f - RAC) * (TAUC * (P - C) - (1.f - TAUC) * C)
                          / (2.f * RAC)) / Q;
        float z = fminf(fmaxf(zu, lo), hi);
        float pin  = TAUC * ((Sp - Bv) - z * (P - C)) + (1.f - TAUC) * (z * C - Bv);
        float quad = Sq2 - 2.f * z * Sq + z * z * Q;
        zout = z;
        return 2.f * (1.f - RAC) * pin + 2.f * RAC * quad;
    };
    float z1 = 0.f, z2 = 0.f;
    const float o1 = evalc(n1, eC1, eB1, z1);
    const float o2 = v2 ? evalc(n2, eC2, eB2, z2) : FLT_MAX;

    float bobj; int bk; float bz;
    if (o2 < o1) { bobj = o2; bk = n2; bz = z2; }
    else         { bobj = o1; bk = n1; bz = z1; }
    // argmin reduction, first-index tiebreak (matches jnp.argmin)
    #pragma unroll
    for (int off = 32; off; off >>= 1) {
        float oo = __shfl_xor(bobj, off);
        int   ok = __shfl_xor(bk,   off);
        float oz = __shfl_xor(bz,   off);
        if (oo < bobj || (oo == bobj && ok < bk)) { bobj = oo; bk = ok; bz = oz; }
    }

    if (lane == 0) out_z[row] = bz;
    out_err[base + n1] = s1 - bz;
    if (v2) out_err[base + n2] = s2 - bz;
}

extern "C" void kernel_launch(void* const* d_in, const int* in_sizes, int n_in,
                              void* d_out, int out_size, void* d_ws, size_t ws_size,
                              hipStream_t stream)
{
    const float* x  = (const float*)d_in[0];
    const float* p[8];
    for (int e = 0; e < 8; ++e) p[e] = (const float*)d_in[1 + e];
    const float* W1 = (const float*)d_in[9];
    const float* b1 = (const float*)d_in[10];
    const float* W2 = (const float*)d_in[11];
    const float* b2 = (const float*)d_in[12];
    const float* W3 = (const float*)d_in[13];
    const float* b3 = (const float*)d_in[14];

    const int B = in_sizes[0] / 64;         // 4096
    float* out_pdf = (float*)d_out;         // [B][101]
    float* out_z   = out_pdf + (size_t)B * N_LOC;   // [B]
    float* out_err = out_z + B;             // [B][101]

    // A/B probe: two identical idempotent launches. Marginal cost of the
    // second launch = true kernel time; remainder = harness replay floor.
    fused4_kernel<<<B / 4, 256, 0, stream>>>(
        x, p[0], p[1], p[2], p[3], p[4], p[5], p[6], p[7],
        W1, b1, W2, b2, W3, b3, out_pdf, out_z, out_err, B);
    fused4_kernel<<<B / 4, 256, 0, stream>>>(
        x, p[0], p[1], p[2], p[3], p[4], p[5], p[6], p[7],
        W1, b1, W2, b2, W3, b3, out_pdf, out_z, out_err, B);
}

// Round 13
// 34.864 us; speedup vs baseline: 1.0767x; 1.0767x over previous
//
#include <hip/hip_runtime.h>
#include <hip/hip_bf16.h>
#include <float.h>

#define N_LOC 101
#define TAUC 0.5f
#define RAC  0.5f
#define EPSV 1e-4f

__device__ __forceinline__ float wsum64(float v) {
    #pragma unroll
    for (int off = 32; off; off >>= 1) v += __shfl_xor(v, off);
    return v;
}

__device__ __forceinline__ void fma4(float* acc, float s, float4 v) {
    acc[0] += s * v.x; acc[1] += s * v.y;
    acc[2] += s * v.z; acc[3] += s * v.w;
}

// ---------------------------------------------------------------------------
// fused4_kernel: identical to round-11 best (K_full ~16.2us, floor ~5.2us).
// This round adds an MLP-ONLY probe kernel (writes gating weights to d_ws)
// to split K_full into K_mlp + K_solve via within-round timing delta.
// ---------------------------------------------------------------------------
__global__ __launch_bounds__(256, 4) void fused4_kernel(
    const float* __restrict__ x,
    const float* __restrict__ p0, const float* __restrict__ p1,
    const float* __restrict__ p2, const float* __restrict__ p3,
    const float* __restrict__ p4, const float* __restrict__ p5,
    const float* __restrict__ p6, const float* __restrict__ p7,
    const float* __restrict__ W1, const float* __restrict__ b1,
    const float* __restrict__ W2, const float* __restrict__ b2,
    const float* __restrict__ W3, const float* __restrict__ b3,
    float* __restrict__ out_pdf, float* __restrict__ out_z,
    float* __restrict__ out_err, int B)
{
    __shared__ float xs [4 * 64];
    __shared__ float hp [2][4 * 132];
    __shared__ float hs1[4 * 132];
    __shared__ float hs2[4 * 132];

    const int t   = threadIdx.x;
    const int r0b = blockIdx.x * 4;

    if (t < 64)
        *reinterpret_cast<float4*>(&xs[t * 4]) =
            *reinterpret_cast<const float4*>(&x[r0b * 64 + t * 4]);
    __syncthreads();

    const int rowg = (t >> 5) & 3;
    const int j0   = (t & 31) * 4;
    const int kh   = t >> 7;

    // ---- phase 1: h1 = relu(x @ W1 + b1), K=64 split 32+32
    {
        float acc[4] = {0.f, 0.f, 0.f, 0.f};
        const int kb = kh * 32;
        #pragma unroll
        for (int kk = 0; kk < 32; ++kk) {
            const float xv = xs[rowg * 64 + kb + kk];
            const float4 w = *reinterpret_cast<const float4*>(&W1[(kb + kk) * 128 + j0]);
            fma4(acc, xv, w);
        }
        float4 o; o.x = acc[0]; o.y = acc[1]; o.z = acc[2]; o.w = acc[3];
        *reinterpret_cast<float4*>(&hp[kh][rowg * 132 + j0]) = o;
    }
    __syncthreads();
    if (t < 128) {
        const int rr = t >> 5, jj = (t & 31) * 4;
        const float4 bv = *reinterpret_cast<const float4*>(&b1[jj]);
        const float4 q0 = *reinterpret_cast<const float4*>(&hp[0][rr * 132 + jj]);
        const float4 q1 = *reinterpret_cast<const float4*>(&hp[1][rr * 132 + jj]);
        float4 o;
        o.x = fmaxf(q0.x + q1.x + bv.x, 0.f);
        o.y = fmaxf(q0.y + q1.y + bv.y, 0.f);
        o.z = fmaxf(q0.z + q1.z + bv.z, 0.f);
        o.w = fmaxf(q0.w + q1.w + bv.w, 0.f);
        *reinterpret_cast<float4*>(&hs1[rr * 132 + jj]) = o;
    }
    __syncthreads();

    // ---- phase 2: h2 = relu(h1 @ W2 + b2), K=128 split 64+64
    {
        float acc[4] = {0.f, 0.f, 0.f, 0.f};
        const int kb = kh * 64;
        #pragma unroll
        for (int kk = 0; kk < 64; ++kk) {
            const float hv = hs1[rowg * 132 + kb + kk];
            const float4 w = *reinterpret_cast<const float4*>(&W2[(kb + kk) * 128 + j0]);
            fma4(acc, hv, w);
        }
        float4 o; o.x = acc[0]; o.y = acc[1]; o.z = acc[2]; o.w = acc[3];
        *reinterpret_cast<float4*>(&hp[kh][rowg * 132 + j0]) = o;
    }
    __syncthreads();
    if (t < 128) {
        const int rr = t >> 5, jj = (t & 31) * 4;
        const float4 bv = *reinterpret_cast<const float4*>(&b2[jj]);
        const float4 q0 = *reinterpret_cast<const float4*>(&hp[0][rr * 132 + jj]);
        const float4 q1 = *reinterpret_cast<const float4*>(&hp[1][rr * 132 + jj]);
        float4 o;
        o.x = fmaxf(q0.x + q1.x + bv.x, 0.f);
        o.y = fmaxf(q0.y + q1.y + bv.y, 0.f);
        o.z = fmaxf(q0.z + q1.z + bv.z, 0.f);
        o.w = fmaxf(q0.w + q1.w + bv.w, 0.f);
        *reinterpret_cast<float4*>(&hs2[rr * 132 + jj]) = o;
    }
    __syncthreads();

    // ---- phase 3 + softmax
    const int wid  = t >> 6;
    const int lane = t & 63;
    const int e    = lane & 7;
    const int kc   = lane >> 3;
    float acc3 = 0.f;
    #pragma unroll
    for (int i = 0; i < 16; ++i)
        acc3 += hs2[wid * 132 + kc * 16 + i] * W3[(kc * 16 + i) * 8 + e];
    acc3 += __shfl_xor(acc3, 8);
    acc3 += __shfl_xor(acc3, 16);
    acc3 += __shfl_xor(acc3, 32);
    const float logit = acc3 + b3[e];
    float m = logit;
    m = fmaxf(m, __shfl_xor(m, 1));
    m = fmaxf(m, __shfl_xor(m, 2));
    m = fmaxf(m, __shfl_xor(m, 4));
    const float ex = expf(logit - m);
    float s = ex;
    s += __shfl_xor(s, 1);
    s += __shfl_xor(s, 2);
    s += __shfl_xor(s, 4);
    const float wgt = ex / s;

    float wv8[8];
    #pragma unroll
    for (int e2 = 0; e2 < 8; ++e2) wv8[e2] = __shfl(wgt, e2);

    // ---- solve: wave wid solves row r0b + wid
    const int row = r0b + wid;
    const long base = (long)row * N_LOC;
    const int n1 = lane, n2 = lane + 64;
    const bool v2 = (n2 < N_LOC);
    const float s1 = n1 * 0.01f, s2 = n2 * 0.01f;

    float pdf1, pdf2;
    {
        const float* pp[8] = { p0+base, p1+base, p2+base, p3+base,
                               p4+base, p5+base, p6+base, p7+base };
        pdf1 = 0.f; pdf2 = 0.f;
        #pragma unroll
        for (int ee = 0; ee < 8; ++ee) {
            pdf1 += wv8[ee] * pp[ee][n1];
            pdf2 += wv8[ee] * (v2 ? pp[ee][n2] : 0.f);
        }
    }
    out_pdf[base + n1] = pdf1;
    if (v2) out_pdf[base + n2] = pdf2;

    const float P   = wsum64(pdf1 + pdf2);
    const float Sp  = wsum64(pdf1*s1  + pdf2*s2);
    const float Sp2 = wsum64(pdf1*s1*s1 + pdf2*s2*s2);
    const float Q   = P   + (float)N_LOC * EPSV;
    const float Sq  = Sp  + 50.5f  * EPSV;
    const float Sq2 = Sp2 + 33.835f * EPSV;

    float ap = pdf1, bp = pdf2, aps = pdf1*s1, bps = pdf2*s2;
    #pragma unroll
    for (int off = 1; off < 64; off <<= 1) {
        float t0 = __shfl_up(ap,  off);
        float t1 = __shfl_up(bp,  off);
        float t2 = __shfl_up(aps, off);
        float t3 = __shfl_up(bps, off);
        if (lane >= off) { ap += t0; bp += t1; aps += t2; bps += t3; }
    }
    const float TaP  = __shfl(ap,  63);
    const float TaPs = __shfl(aps, 63);
    float eC1 = __shfl_up(ap,  1); if (lane == 0) eC1 = 0.f;
    float eB1 = __shfl_up(aps, 1); if (lane == 0) eB1 = 0.f;
    float eC2 = __shfl_up(bp,  1); if (lane == 0) eC2 = 0.f;
    float eB2 = __shfl_up(bps, 1); if (lane == 0) eB2 = 0.f;
    eC2 += TaP; eB2 += TaPs;

    auto evalc = [&](int k, float C, float Bv, float& zout) -> float {
        const float lo = (k == 0)   ? 0.f : (k - 1) * 0.01f;
        const float hi = (k <= 100) ? k * 0.01f : 1.f;
        float zu = (Sq + (1.f - RAC) * (TAUC * (P - C) - (1.f - TAUC) * C)
                          / (2.f * RAC)) / Q;
        float z = fminf(fmaxf(zu, lo), hi);
        float pin  = TAUC * ((Sp - Bv) - z * (P - C)) + (1.f - TAUC) * (z * C - Bv);
        float quad = Sq2 - 2.f * z * Sq + z * z * Q;
        zout = z;
        return 2.f * (1.f - RAC) * pin + 2.f * RAC * quad;
    };
    float z1 = 0.f, z2 = 0.f;
    const float o1 = evalc(n1, eC1, eB1, z1);
    const float o2 = v2 ? evalc(n2, eC2, eB2, z2) : FLT_MAX;

    float bobj; int bk; float bz;
    if (o2 < o1) { bobj = o2; bk = n2; bz = z2; }
    else         { bobj = o1; bk = n1; bz = z1; }
    #pragma unroll
    for (int off = 32; off; off >>= 1) {
        float oo = __shfl_xor(bobj, off);
        int   ok = __shfl_xor(bk,   off);
        float oz = __shfl_xor(bz,   off);
        if (oo < bobj || (oo == bobj && ok < bk)) { bobj = oo; bk = ok; bz = oz; }
    }

    if (lane == 0) out_z[row] = bz;
    out_err[base + n1] = s1 - bz;
    if (v2) out_err[base + n2] = s2 - bz;
}

// ---------------------------------------------------------------------------
// MLP-ONLY probe: byte-identical MLP+softmax path, stops after the gating
// weights and writes them to d_ws. Timing delta vs round-11 isolates K_mlp.
// ---------------------------------------------------------------------------
__global__ __launch_bounds__(256, 4) void mlp_probe_kernel(
    const float* __restrict__ x,
    const float* __restrict__ W1, const float* __restrict__ b1,
    const float* __restrict__ W2, const float* __restrict__ b2,
    const float* __restrict__ W3, const float* __restrict__ b3,
    float* __restrict__ wout, int B)
{
    __shared__ float xs [4 * 64];
    __shared__ float hp [2][4 * 132];
    __shared__ float hs1[4 * 132];
    __shared__ float hs2[4 * 132];

    const int t   = threadIdx.x;
    const int r0b = blockIdx.x * 4;

    if (t < 64)
        *reinterpret_cast<float4*>(&xs[t * 4]) =
            *reinterpret_cast<const float4*>(&x[r0b * 64 + t * 4]);
    __syncthreads();

    const int rowg = (t >> 5) & 3;
    const int j0   = (t & 31) * 4;
    const int kh   = t >> 7;

    {
        float acc[4] = {0.f, 0.f, 0.f, 0.f};
        const int kb = kh * 32;
        #pragma unroll
        for (int kk = 0; kk < 32; ++kk) {
            const float xv = xs[rowg * 64 + kb + kk];
            const float4 w = *reinterpret_cast<const float4*>(&W1[(kb + kk) * 128 + j0]);
            fma4(acc, xv, w);
        }
        float4 o; o.x = acc[0]; o.y = acc[1]; o.z = acc[2]; o.w = acc[3];
        *reinterpret_cast<float4*>(&hp[kh][rowg * 132 + j0]) = o;
    }
    __syncthreads();
    if (t < 128) {
        const int rr = t >> 5, jj = (t & 31) * 4;
        const float4 bv = *reinterpret_cast<const float4*>(&b1[jj]);
        const float4 q0 = *reinterpret_cast<const float4*>(&hp[0][rr * 132 + jj]);
        const float4 q1 = *reinterpret_cast<const float4*>(&hp[1][rr * 132 + jj]);
        float4 o;
        o.x = fmaxf(q0.x + q1.x + bv.x, 0.f);
        o.y = fmaxf(q0.y + q1.y + bv.y, 0.f);
        o.z = fmaxf(q0.z + q1.z + bv.z, 0.f);
        o.w = fmaxf(q0.w + q1.w + bv.w, 0.f);
        *reinterpret_cast<float4*>(&hs1[rr * 132 + jj]) = o;
    }
    __syncthreads();

    {
        float acc[4] = {0.f, 0.f, 0.f, 0.f};
        const int kb = kh * 64;
        #pragma unroll
        for (int kk = 0; kk < 64; ++kk) {
            const float hv = hs1[rowg * 132 + kb + kk];
            const float4 w = *reinterpret_cast<const float4*>(&W2[(kb + kk) * 128 + j0]);
            fma4(acc, hv, w);
        }
        float4 o; o.x = acc[0]; o.y = acc[1]; o.z = acc[2]; o.w = acc[3];
        *reinterpret_cast<float4*>(&hp[kh][rowg * 132 + j0]) = o;
    }
    __syncthreads();
    if (t < 128) {
        const int rr = t >> 5, jj = (t & 31) * 4;
        const float4 bv = *reinterpret_cast<const float4*>(&b2[jj]);
        const float4 q0 = *reinterpret_cast<const float4*>(&hp[0][rr * 132 + jj]);
        const float4 q1 = *reinterpret_cast<const float4*>(&hp[1][rr * 132 + jj]);
        float4 o;
        o.x = fmaxf(q0.x + q1.x + bv.x, 0.f);
        o.y = fmaxf(q0.y + q1.y + bv.y, 0.f);
        o.z = fmaxf(q0.z + q1.z + bv.z, 0.f);
        o.w = fmaxf(q0.w + q1.w + bv.w, 0.f);
        *reinterpret_cast<float4*>(&hs2[rr * 132 + jj]) = o;
    }
    __syncthreads();

    const int wid  = t >> 6;
    const int lane = t & 63;
    const int e    = lane & 7;
    const int kc   = lane >> 3;
    float acc3 = 0.f;
    #pragma unroll
    for (int i = 0; i < 16; ++i)
        acc3 += hs2[wid * 132 + kc * 16 + i] * W3[(kc * 16 + i) * 8 + e];
    acc3 += __shfl_xor(acc3, 8);
    acc3 += __shfl_xor(acc3, 16);
    acc3 += __shfl_xor(acc3, 32);
    const float logit = acc3 + b3[e];
    float m = logit;
    m = fmaxf(m, __shfl_xor(m, 1));
    m = fmaxf(m, __shfl_xor(m, 2));
    m = fmaxf(m, __shfl_xor(m, 4));
    const float ex = expf(logit - m);
    float s = ex;
    s += __shfl_xor(s, 1);
    s += __shfl_xor(s, 2);
    s += __shfl_xor(s, 4);
    const float wgt = ex / s;

    const int row = r0b + wid;
    if (lane < 8) wout[(long)row * 8 + lane] = wgt;   // kc==0 lanes hold e=lane
}

extern "C" void kernel_launch(void* const* d_in, const int* in_sizes, int n_in,
                              void* d_out, int out_size, void* d_ws, size_t ws_size,
                              hipStream_t stream)
{
    const float* x  = (const float*)d_in[0];
    const float* p[8];
    for (int e = 0; e < 8; ++e) p[e] = (const float*)d_in[1 + e];
    const float* W1 = (const float*)d_in[9];
    const float* b1 = (const float*)d_in[10];
    const float* W2 = (const float*)d_in[11];
    const float* b2 = (const float*)d_in[12];
    const float* W3 = (const float*)d_in[13];
    const float* b3 = (const float*)d_in[14];

    const int B = in_sizes[0] / 64;         // 4096
    float* out_pdf = (float*)d_out;         // [B][101]
    float* out_z   = out_pdf + (size_t)B * N_LOC;   // [B]
    float* out_err = out_z + B;             // [B][101]
    float* wprobe  = (float*)d_ws;          // [B][8] probe dump

    // Launch 1: real kernel (validated output). Launch 2: MLP-only probe.
    // dur - 21.4us (this container's floor+K_full) ~= K_mlp.
    fused4_kernel<<<B / 4, 256, 0, stream>>>(
        x, p[0], p[1], p[2], p[3], p[4], p[5], p[6], p[7],
        W1, b1, W2, b2, W3, b3, out_pdf, out_z, out_err, B);
    mlp_probe_kernel<<<B / 4, 256, 0, stream>>>(
        x, W1, b1, W2, b2, W3, b3, wprobe, B);
}

// Round 14
// 15.625 us; speedup vs baseline: 2.4025x; 2.2312x over previous
//
#include <hip/hip_runtime.h>
#include <hip/hip_bf16.h>
#include <float.h>

#define N_LOC 101
#define TAUC 0.5f
#define RAC  0.5f
#define EPSV 1e-4f

__device__ __forceinline__ float wsum64(float v) {
    #pragma unroll
    for (int off = 32; off; off >>= 1) v += __shfl_xor(v, off);
    return v;
}

__device__ __forceinline__ void fma4(float* acc, float s, float4 v) {
    acc[0] += s * v.x; acc[1] += s * v.y;
    acc[2] += s * v.z; acc[3] += s * v.w;
}

// ---------------------------------------------------------------------------
// fused8_kernel: 8 rows/block, grid = B/8 = 512, 256 threads (4 waves).
// MLP with M_r=8 register reuse: thread (jg = t&31, kh = t>>5) loads each
// W float4 ONCE and applies it to all 8 rows (acc[8][4], static indexing).
// Each W element is read exactly once per block (48 MB total vs 192 MB in
// fused4). K-split partials reduced via 32 KB LDS hp buffer. Phase 3 +
// softmax + solve: wave wid handles rows wid*2 .. wid*2+1 (verified math).
// LDS 42 KB -> 2 blocks/CU (grid-capped), 8 waves/CU.
// ---------------------------------------------------------------------------
__global__ __launch_bounds__(256, 2) void fused8_kernel(
    const float* __restrict__ x,
    const float* __restrict__ p0, const float* __restrict__ p1,
    const float* __restrict__ p2, const float* __restrict__ p3,
    const float* __restrict__ p4, const float* __restrict__ p5,
    const float* __restrict__ p6, const float* __restrict__ p7,
    const float* __restrict__ W1, const float* __restrict__ b1,
    const float* __restrict__ W2, const float* __restrict__ b2,
    const float* __restrict__ W3, const float* __restrict__ b3,
    float* __restrict__ out_pdf, float* __restrict__ out_z,
    float* __restrict__ out_err, int B)
{
    __shared__ float xs [8 * 64];       // 2 KB
    __shared__ float hp [8][8 * 128];   // 32 KB K-split partials
    __shared__ float h1s[8 * 128];      // 4 KB
    __shared__ float h2s[8 * 128];      // 4 KB

    const int t   = threadIdx.x;
    const int r0b = blockIdx.x * 8;

    // ---- stage x tile (8 x 64 = 512 floats)
    if (t < 128)
        *reinterpret_cast<float4*>(&xs[t * 4]) =
            *reinterpret_cast<const float4*>(&x[r0b * 64 + t * 4]);
    __syncthreads();

    const int jg = t & 31;
    const int j0 = jg * 4;
    const int kh = t >> 5;              // 0..7 K-chunk

    // ---- phase 1: h1 = relu(x @ W1 + b1), K=64, 8 kk per chunk, M_r=8
    {
        float acc[8][4] = {};
        const int kb = kh * 8;
        #pragma unroll
        for (int kq = 0; kq < 8; kq += 4) {
            float4 w[4];
            #pragma unroll
            for (int q = 0; q < 4; ++q)
                w[q] = *reinterpret_cast<const float4*>(&W1[(kb + kq + q) * 128 + j0]);
            #pragma unroll
            for (int r = 0; r < 8; ++r) {
                const float4 xv = *reinterpret_cast<const float4*>(&xs[r * 64 + kb + kq]);
                fma4(acc[r], xv.x, w[0]);
                fma4(acc[r], xv.y, w[1]);
                fma4(acc[r], xv.z, w[2]);
                fma4(acc[r], xv.w, w[3]);
            }
        }
        #pragma unroll
        for (int r = 0; r < 8; ++r) {
            float4 o; o.x = acc[r][0]; o.y = acc[r][1]; o.z = acc[r][2]; o.w = acc[r][3];
            *reinterpret_cast<float4*>(&hp[kh][r * 128 + j0]) = o;
        }
    }
    __syncthreads();
    {   // reduce 8 partials + bias + relu -> h1s (one float4 per thread)
        const int r  = t >> 5;
        const int jj = (t & 31) * 4;
        float4 a = *reinterpret_cast<const float4*>(&b1[jj]);
        #pragma unroll
        for (int k2 = 0; k2 < 8; ++k2) {
            const float4 q = *reinterpret_cast<const float4*>(&hp[k2][r * 128 + jj]);
            a.x += q.x; a.y += q.y; a.z += q.z; a.w += q.w;
        }
        float4 o;
        o.x = fmaxf(a.x, 0.f); o.y = fmaxf(a.y, 0.f);
        o.z = fmaxf(a.z, 0.f); o.w = fmaxf(a.w, 0.f);
        *reinterpret_cast<float4*>(&h1s[r * 128 + jj]) = o;
    }
    __syncthreads();

    // ---- phase 2: h2 = relu(h1 @ W2 + b2), K=128, 16 kk per chunk, M_r=8
    {
        float acc[8][4] = {};
        const int kb = kh * 16;
        #pragma unroll
        for (int kq = 0; kq < 16; kq += 4) {
            float4 w[4];
            #pragma unroll
            for (int q = 0; q < 4; ++q)
                w[q] = *reinterpret_cast<const float4*>(&W2[(kb + kq + q) * 128 + j0]);
            #pragma unroll
            for (int r = 0; r < 8; ++r) {
                const float4 hv = *reinterpret_cast<const float4*>(&h1s[r * 128 + kb + kq]);
                fma4(acc[r], hv.x, w[0]);
                fma4(acc[r], hv.y, w[1]);
                fma4(acc[r], hv.z, w[2]);
                fma4(acc[r], hv.w, w[3]);
            }
        }
        #pragma unroll
        for (int r = 0; r < 8; ++r) {
            float4 o; o.x = acc[r][0]; o.y = acc[r][1]; o.z = acc[r][2]; o.w = acc[r][3];
            *reinterpret_cast<float4*>(&hp[kh][r * 128 + j0]) = o;
        }
    }
    __syncthreads();
    {   // reduce + bias + relu -> h2s
        const int r  = t >> 5;
        const int jj = (t & 31) * 4;
        float4 a = *reinterpret_cast<const float4*>(&b2[jj]);
        #pragma unroll
        for (int k2 = 0; k2 < 8; ++k2) {
            const float4 q = *reinterpret_cast<const float4*>(&hp[k2][r * 128 + jj]);
            a.x += q.x; a.y += q.y; a.z += q.z; a.w += q.w;
        }
        float4 o;
        o.x = fmaxf(a.x, 0.f); o.y = fmaxf(a.y, 0.f);
        o.z = fmaxf(a.z, 0.f); o.w = fmaxf(a.w, 0.f);
        *reinterpret_cast<float4*>(&h2s[r * 128 + jj]) = o;
    }
    __syncthreads();

    // ---- per-wave: rows wid*2 + rr (rr = 0,1): phase 3 + softmax + solve
    const int wid  = t >> 6;
    const int lane = t & 63;
    const int e    = lane & 7;
    const int kc   = lane >> 3;
    const int n1 = lane, n2 = lane + 64;
    const bool v2 = (n2 < N_LOC);
    const float s1 = n1 * 0.01f, s2 = n2 * 0.01f;

    for (int rr = 0; rr < 2; ++rr) {
        const int rl  = wid * 2 + rr;       // 0..7
        const int row = r0b + rl;

        // phase 3: logits via (e, kc) decomposition
        float acc3 = 0.f;
        #pragma unroll
        for (int i = 0; i < 16; ++i)
            acc3 += h2s[rl * 128 + kc * 16 + i] * W3[(kc * 16 + i) * 8 + e];
        acc3 += __shfl_xor(acc3, 8);
        acc3 += __shfl_xor(acc3, 16);
        acc3 += __shfl_xor(acc3, 32);
        const float logit = acc3 + b3[e];
        float m = logit;
        m = fmaxf(m, __shfl_xor(m, 1));
        m = fmaxf(m, __shfl_xor(m, 2));
        m = fmaxf(m, __shfl_xor(m, 4));
        const float ex = expf(logit - m);
        float s = ex;
        s += __shfl_xor(s, 1);
        s += __shfl_xor(s, 2);
        s += __shfl_xor(s, 4);
        const float wgt = ex / s;

        float wv8[8];
        #pragma unroll
        for (int e2 = 0; e2 < 8; ++e2) wv8[e2] = __shfl(wgt, e2);

        // solve (verified closed-form)
        const long base = (long)row * N_LOC;
        float pdf1, pdf2;
        {
            const float* pp[8] = { p0+base, p1+base, p2+base, p3+base,
                                   p4+base, p5+base, p6+base, p7+base };
            pdf1 = 0.f; pdf2 = 0.f;
            #pragma unroll
            for (int ee = 0; ee < 8; ++ee) {
                pdf1 += wv8[ee] * pp[ee][n1];
                pdf2 += wv8[ee] * (v2 ? pp[ee][n2] : 0.f);
            }
        }
        out_pdf[base + n1] = pdf1;
        if (v2) out_pdf[base + n2] = pdf2;

        const float P   = wsum64(pdf1 + pdf2);
        const float Sp  = wsum64(pdf1*s1  + pdf2*s2);
        const float Sp2 = wsum64(pdf1*s1*s1 + pdf2*s2*s2);
        const float Q   = P   + (float)N_LOC * EPSV;
        const float Sq  = Sp  + 50.5f  * EPSV;
        const float Sq2 = Sp2 + 33.835f * EPSV;

        float ap = pdf1, bp = pdf2, aps = pdf1*s1, bps = pdf2*s2;
        #pragma unroll
        for (int off = 1; off < 64; off <<= 1) {
            float t0 = __shfl_up(ap,  off);
            float t1 = __shfl_up(bp,  off);
            float t2 = __shfl_up(aps, off);
            float t3 = __shfl_up(bps, off);
            if (lane >= off) { ap += t0; bp += t1; aps += t2; bps += t3; }
        }
        const float TaP  = __shfl(ap,  63);
        const float TaPs = __shfl(aps, 63);
        float eC1 = __shfl_up(ap,  1); if (lane == 0) eC1 = 0.f;
        float eB1 = __shfl_up(aps, 1); if (lane == 0) eB1 = 0.f;
        float eC2 = __shfl_up(bp,  1); if (lane == 0) eC2 = 0.f;
        float eB2 = __shfl_up(bps, 1); if (lane == 0) eB2 = 0.f;
        eC2 += TaP; eB2 += TaPs;

        auto evalc = [&](int k, float C, float Bv, float& zout) -> float {
            const float lo = (k == 0)   ? 0.f : (k - 1) * 0.01f;
            const float hi = (k <= 100) ? k * 0.01f : 1.f;
            float zu = (Sq + (1.f - RAC) * (TAUC * (P - C) - (1.f - TAUC) * C)
                              / (2.f * RAC)) / Q;
            float z = fminf(fmaxf(zu, lo), hi);
            float pin  = TAUC * ((Sp - Bv) - z * (P - C)) + (1.f - TAUC) * (z * C - Bv);
            float quad = Sq2 - 2.f * z * Sq + z * z * Q;
            zout = z;
            return 2.f * (1.f - RAC) * pin + 2.f * RAC * quad;
        };
        float z1 = 0.f, z2 = 0.f;
        const float o1 = evalc(n1, eC1, eB1, z1);
        const float o2 = v2 ? evalc(n2, eC2, eB2, z2) : FLT_MAX;

        float bobj; int bk; float bz;
        if (o2 < o1) { bobj = o2; bk = n2; bz = z2; }
        else         { bobj = o1; bk = n1; bz = z1; }
        #pragma unroll
        for (int off = 32; off; off >>= 1) {
            float oo = __shfl_xor(bobj, off);
            int   ok = __shfl_xor(bk,   off);
            float oz = __shfl_xor(bz,   off);
            if (oo < bobj || (oo == bobj && ok < bk)) { bobj = oo; bk = ok; bz = oz; }
        }

        if (lane == 0) out_z[row] = bz;
        out_err[base + n1] = s1 - bz;
        if (v2) out_err[base + n2] = s2 - bz;
    }
}

extern "C" void kernel_launch(void* const* d_in, const int* in_sizes, int n_in,
                              void* d_out, int out_size, void* d_ws, size_t ws_size,
                              hipStream_t stream)
{
    const float* x  = (const float*)d_in[0];
    const float* p[8];
    for (int e = 0; e < 8; ++e) p[e] = (const float*)d_in[1 + e];
    const float* W1 = (const float*)d_in[9];
    const float* b1 = (const float*)d_in[10];
    const float* W2 = (const float*)d_in[11];
    const float* b2 = (const float*)d_in[12];
    const float* W3 = (const float*)d_in[13];
    const float* b3 = (const float*)d_in[14];

    const int B = in_sizes[0] / 64;         // 4096
    float* out_pdf = (float*)d_out;         // [B][101]
    float* out_z   = out_pdf + (size_t)B * N_LOC;   // [B]
    float* out_err = out_z + B;             // [B][101]

    fused8_kernel<<<B / 8, 256, 0, stream>>>(
        x, p[0], p[1], p[2], p[3], p[4], p[5], p[6], p[7],
        W1, b1, W2, b2, W3, b3, out_pdf, out_z, out_err, B);
}